// Round 17
// baseline (467.814 us; speedup 1.0000x reference)
//
#include <hip/hip_runtime.h>
#include <hip/hip_bf16.h>

#define N_FLOWS 50000
#define N_LINKS 5000
#define LPATH 8
#define PLINK 80
#define DIM 16
#define ITERS 12

typedef __attribute__((ext_vector_type(4))) float f32x4;
typedef __attribute__((ext_vector_type(8))) short bf16x8;

#define L2E 1.4426950408889634f
#define NL2E (-1.4426950408889634f)
#define P2L2E 2.8853900817779268f

#define SWZ(x, pat) __int_as_float(__builtin_amdgcn_ds_swizzle(__float_as_int(x), (pat)))
#define MFMA16(A, B, C) __builtin_amdgcn_mfma_f32_16x16x32_bf16((A), (B), (C), 0, 0, 0)

template <int CTRL>
__device__ __forceinline__ float dppmov_(float x) {
    return __int_as_float(__builtin_amdgcn_update_dpp(
        0, __float_as_int(x), CTRL, 0xF, 0xF, true));
}
#define ROR1 0x121
#define ROR2 0x122
#define ROR4 0x124
#define ROR8 0x128

__device__ __forceinline__ float rcp_(float x) { return __builtin_amdgcn_rcpf(x); }
__device__ __forceinline__ float exp2_(float x) { return __builtin_amdgcn_exp2f(x); }
__device__ __forceinline__ float sigmoid2_(float s) { return rcp_(1.f + exp2_(s)); }
__device__ __forceinline__ float tanh2_(float s) { return 1.f - 2.f * rcp_(1.f + exp2_(s)); }
__device__ __forceinline__ float selu_(float x) {
    const float sc = 1.0507009873554805f, al = 1.6732632423543772f;
    return x > 0.f ? sc * x : sc * al * expm1f(x);
}
__device__ __forceinline__ float softplus_(float x) {
    return fmaxf(x, 0.f) + log1pf(__expf(-fabsf(x)));
}
__device__ __forceinline__ ushort f2bf_(float x) {
    unsigned u = __float_as_uint(x);
    u += 0x7fffu + ((u >> 16) & 1u);
    return (ushort)(u >> 16);
}
__device__ __forceinline__ float bf2f_(ushort h) {
    return __uint_as_float(((unsigned)h) << 16);
}

// ---- one-time weight repack ----------------------------------------------
// wfrag[gate*2+isLo][lane][e]: B-frag with INTERLEAVED K-order: slot k holds
// W[k>>1][n] (each W row repeated at k=2m,2m+1) so A=[hi0,lo0,hi1,lo1,...]
// pairs sum hi+lo contributions per row. hi frag = bf16(W*sc); lo = remainder.
__global__ __launch_bounds__(256) void k_prep(
    const float* __restrict__ pWr, const float* __restrict__ attW,
    const float* __restrict__ lWk, const float* __restrict__ lWr,
    const float* __restrict__ pWk,
    ushort* __restrict__ wfrag, float* __restrict__ lWk_t,
    float* __restrict__ lWr_t, float* __restrict__ pWk_t) {
    int i = blockIdx.x * 256 + threadIdx.x;
    if (i < 768) {
        int t = i;
        int j = t / 48, r = t % 48;
        float sc = (r / 16) == 2 ? P2L2E : NL2E;
        lWk_t[t] = lWk[(r % 16) * 48 + (r / 16) * 16 + j] * sc;
    } else if (i < 1536) {
        int t = i - 768;
        int j = t / 48, r = t % 48;
        float sc = (r / 16) == 2 ? P2L2E : NL2E;
        lWr_t[t] = lWr[(r % 16) * 48 + (r / 16) * 16 + j] * sc;
    } else if (i < 2304) {
        int t = i - 1536;
        pWk_t[t] = pWk[(t % 16) * 48 + (t / 16)];
    } else if (i < 6400) {
        int t = i - 2304;            // 0..4095
        int frag = t >> 9;           // 0..7 = gate*2 + isLo
        int s = t & 511;
        int lane = s >> 3;
        int e = s & 7;
        int gate = frag >> 1;
        int isLo = frag & 1;
        int n = lane & 15;
        int k = (lane >> 4) * 8 + e; // 0..31
        int m = k >> 1;              // W row (repeated across k pairs)
        float raw;
        if (gate < 3) {
            float sc = gate == 2 ? P2L2E : NL2E;
            raw = pWr[m * 48 + gate * 16 + n] * sc;
        } else {
            raw = attW[m * 16 + n] * L2E;
        }
        ushort hi = f2bf_(raw);
        wfrag[t] = isLo ? f2bf_(raw - bf2f_(hi)) : hi;
    }
}

// ---- load per link -------------------------------------------------------
__global__ __launch_bounds__(256) void k_load(const int* __restrict__ p2l,
                                              const float* __restrict__ flow_traffic,
                                              const float* __restrict__ link_capacity,
                                              float* __restrict__ load) {
    int wave = (blockIdx.x * 256 + threadIdx.x) >> 6;
    int lane = threadIdx.x & 63;
    if (wave >= N_LINKS) return;
    float s = 0.f;
    for (int p = lane; p < PLINK; p += 64) {
        int flow = p2l[(wave * PLINK + p) * 2];
        s += flow_traffic[flow];
    }
#pragma unroll
    for (int off = 32; off; off >>= 1) s += __shfl_xor(s, off, 64);
    if (lane == 0) load[wave] = s / (link_capacity[wave] * 1e9f);
}

// ---- flow embedding ------------------------------------------------------
__global__ __launch_bounds__(256) void k_flow_init(
    const float* __restrict__ flow_traffic, const float* __restrict__ flow_packets,
    const float* __restrict__ ibg, const float* __restrict__ rate,
    const float* __restrict__ p90, const float* __restrict__ pkt_size,
    const float* __restrict__ bitrate_pb, const float* __restrict__ ipg_mean,
    const float* __restrict__ ipg_var, const float* __restrict__ pkts_pb,
    const int* __restrict__ flow_length, const float* __restrict__ flow_type,
    const float* __restrict__ W1, const float* __restrict__ b1,
    const float* __restrict__ W2, const float* __restrict__ b2,
    float* __restrict__ path_state) {
    int f = blockIdx.x * 256 + threadIdx.x;
    if (f >= N_FLOWS) return;
    float feats[13];
    feats[0] = (flow_traffic[f] - 0.1f) * 2.f;
    feats[1] = (flow_packets[f] - 0.1f) * 2.f;
    feats[2] = (ibg[f] - 0.1f) * 2.f;
    feats[3] = (rate[f] - 0.1f) * 2.f;
    feats[4] = (p90[f] - 0.1f) * 2.f;
    feats[5] = (pkt_size[f] - 0.1f) * 2.f;
    feats[6] = (bitrate_pb[f] - 0.1f) * 2.f;
    feats[7] = (ipg_mean[f] - 0.1f) * 2.f;
    feats[8] = (ipg_var[f] - 0.1f) * 2.f;
    feats[9] = (pkts_pb[f] - 0.1f) * 2.f;
    feats[10] = (float)flow_length[f];
    feats[11] = flow_type[f * 2 + 0];
    feats[12] = flow_type[f * 2 + 1];
    float h1[DIM];
#pragma unroll
    for (int j = 0; j < DIM; ++j) {
        float a = b1[j];
#pragma unroll
        for (int k = 0; k < 13; ++k) a = fmaf(feats[k], W1[k * DIM + j], a);
        h1[j] = selu_(a);
    }
#pragma unroll
    for (int j = 0; j < DIM; ++j) {
        float a = b2[j];
#pragma unroll
        for (int k = 0; k < DIM; ++k) a = fmaf(h1[k], W2[k * DIM + j], a);
        path_state[f * DIM + j] = selu_(a);
    }
}

// ---- link embedding + xform precompute (identical to r13) ----------------
__global__ __launch_bounds__(256) void k_link_init(
    const float* __restrict__ link_capacity, const float* __restrict__ load,
    const float* __restrict__ max_link_load,
    const float* __restrict__ W1, const float* __restrict__ b1,
    const float* __restrict__ W2, const float* __restrict__ b2,
    const float* __restrict__ pWk, const float* __restrict__ pb,
    float* __restrict__ link_state, float* __restrict__ xform) {
    int l = blockIdx.x * 256 + threadIdx.x;
    if (l >= N_LINKS) return;
    float feats[3];
    feats[0] = (link_capacity[l] - 0.1f) * 2.f;
    feats[1] = load[l];
    feats[2] = load[l] / max_link_load[0];
    float h1[DIM];
#pragma unroll
    for (int j = 0; j < DIM; ++j) {
        float a = b1[j];
#pragma unroll
        for (int k = 0; k < 3; ++k) a = fmaf(feats[k], W1[k * DIM + j], a);
        h1[j] = selu_(a);
    }
    float h2[DIM];
#pragma unroll
    for (int j = 0; j < DIM; ++j) {
        float a = b2[j];
#pragma unroll
        for (int k = 0; k < DIM; ++k) a = fmaf(h1[k], W2[k * DIM + j], a);
        h2[j] = selu_(a);
        link_state[l * DIM + j] = h2[j];
    }
#pragma unroll
    for (int c = 0; c < 3 * DIM; ++c) {
        float a = (c < 32) ? (pb[c] + pb[48 + c]) : pb[c];
#pragma unroll
        for (int k = 0; k < DIM; ++k) a = fmaf(h2[k], pWk[k * 48 + c], a);
        float sc = (c < 32) ? NL2E : P2L2E;
        xform[l * 64 + (c & 15) * 4 + (c >> 4)] = a * sc;
    }
}

// ---- flow pass: MFMA GRU (double-bf16, interleaved hi/lo pairs) ----------
// C/D layout: col j = lane&15, row flow = (lane>>4)*4 + reg.
// A k-order: [hi0,lo0,hi1,lo1,...] -> ONE packed b32 LDS write per (r).
template <bool LAST>
__global__ __launch_bounds__(256) void k_flow_pass(
    const int* __restrict__ l2p, const float* __restrict__ xform,
    float* __restrict__ path_state, ushort* __restrict__ svb,
    float* __restrict__ svf,
    const ushort* __restrict__ wfrag, const float* __restrict__ b,
    const float* __restrict__ attB) {
    __shared__ __align__(16) unsigned hx[4][16][20];  // row = 20 uints = 80B
    __shared__ int lnk[4][16][8];
    int tid = threadIdx.x;
    int wid = tid >> 6, lane = tid & 63;
    int g = lane >> 4, j = lane & 15;
    int fbase = blockIdx.x * 64 + wid * 16;
    {   // stage this wave's 16x8 link table (wave-private, no barrier needed)
        int lf = lane >> 2;
        int off = (lane & 3) * 2;
        int fc = fbase + lf; if (fc >= N_FLOWS) fc = N_FLOWS - 1;
        *(int2*)&lnk[wid][lf][off] = *(const int2*)(l2p + fc * LPATH + off);
    }
    bf16x8 WzH = *(const bf16x8*)(wfrag + (0 * 512 + lane * 8));
    bf16x8 WzL = *(const bf16x8*)(wfrag + (1 * 512 + lane * 8));
    bf16x8 WrH = *(const bf16x8*)(wfrag + (2 * 512 + lane * 8));
    bf16x8 WrL = *(const bf16x8*)(wfrag + (3 * 512 + lane * 8));
    bf16x8 WhH = *(const bf16x8*)(wfrag + (4 * 512 + lane * 8));
    bf16x8 WhL = *(const bf16x8*)(wfrag + (5 * 512 + lane * 8));
    bf16x8 WaH = *(const bf16x8*)(wfrag + (6 * 512 + lane * 8));
    bf16x8 WaL = *(const bf16x8*)(wfrag + (7 * 512 + lane * 8));
    float bh = P2L2E * b[80 + j];
    float ab = L2E * attB[j];
    f32x4 bhv = {bh, bh, bh, bh};
    f32x4 abv = {ab, ab, ab, ab};
    f32x4 zero = {0.f, 0.f, 0.f, 0.f};
    int fr[4];
    f32x4 hC;
#pragma unroll
    for (int r = 0; r < 4; ++r) {
        fr[r] = fbase + g * 4 + r;
        int fc = fr[r] < N_FLOWS ? fr[r] : N_FLOWS - 1;
        hC[r] = path_state[fc * DIM + j];
    }
#pragma unroll
    for (int p = 0; p <= LPATH; ++p) {
        bf16x8 A = {};
        if (!LAST || p < LPATH) {
            // split h -> (hi,lo) pair, ONE b32 store per r; A-frag = b128 read
#pragma unroll
            for (int r = 0; r < 4; ++r) {
                unsigned hi = f2bf_(hC[r]);
                unsigned lo = f2bf_(hC[r] - bf2f_((ushort)hi));
                hx[wid][g * 4 + r][j] = (lo << 16) | hi;
            }
            A = *(const bf16x8*)&hx[wid][j][g * 4];
        }
        if constexpr (!LAST) {
            f32x4 att = MFMA16(A, WaH, abv);
            att = MFMA16(A, WaL, att);
#pragma unroll
            for (int r = 0; r < 4; ++r) {
                float a = att[r];
                a = a > 0.f ? a : 0.01f * a;  // leaky (scale-safe)
                float m = a;
                m = fmaxf(m, dppmov_<ROR1>(m));
                m = fmaxf(m, dppmov_<ROR2>(m));
                m = fmaxf(m, dppmov_<ROR4>(m));
                m = fmaxf(m, dppmov_<ROR8>(m));
                float e = exp2_(a - m);
                float s = e;
                s += dppmov_<ROR1>(s);
                s += dppmov_<ROR2>(s);
                s += dppmov_<ROR4>(s);
                s += dppmov_<ROR8>(s);
                if (fr[r] < N_FLOWS)
                    svb[p * (N_FLOWS * DIM) + fr[r] * DIM + j] =
                        f2bf_(e * rcp_(s) * hC[r]);
            }
        } else {
            if (p > 0) {
#pragma unroll
                for (int r = 0; r < 4; ++r)
                    if (fr[r] < N_FLOWS)
                        svf[p * (N_FLOWS * DIM) + fr[r] * DIM + j] = hC[r];
            }
        }
        if (p < LPATH) {
            f32x4 Gz = MFMA16(A, WzH, zero);
            Gz = MFMA16(A, WzL, Gz);
            f32x4 Gr = MFMA16(A, WrH, zero);
            Gr = MFMA16(A, WrL, Gr);
            f32x4 Gh = MFMA16(A, WhH, bhv);
            Gh = MFMA16(A, WhL, Gh);
#pragma unroll
            for (int r = 0; r < 4; ++r) {
                int link = lnk[wid][g * 4 + r][p];
                f32x4 xq = *(const f32x4*)(xform + link * 64 + j * 4);
                float z = sigmoid2_(xq[0] + Gz[r]);
                float rr = sigmoid2_(xq[1] + Gr[r]);
                float cand = tanh2_(fmaf(rr, Gh[r], xq[2]));
                hC[r] = fmaf(z, hC[r] - cand, cand);
            }
        }
    }
    if constexpr (!LAST) {
#pragma unroll
        for (int r = 0; r < 4; ++r)
            if (fr[r] < N_FLOWS) path_state[fr[r] * DIM + j] = hC[r];
    }
}

// ---- link pass: bf16 gather-sum + link GRU (exp2 gates) + fused xform ----
__global__ __launch_bounds__(256, 4) void k_link_pass(
    const int* __restrict__ p2l, const ushort* __restrict__ svb,
    float* __restrict__ link_state,
    const float* __restrict__ lWk_t, const float* __restrict__ lWr_t,
    const float* __restrict__ b,
    const float* __restrict__ pWk_t, const float* __restrict__ pb,
    float* __restrict__ xform) {
    __shared__ float xb_[4][16];
    __shared__ float hb_[4][16];
    int tid = threadIdx.x;
    int li = tid >> 6;
    int lane = tid & 63;
    int sl = lane >> 4, j = lane & 15;
    int link = blockIdx.x * 4 + li;
    float ps = 0.f;
#pragma unroll 4
    for (int i = 0; i < PLINK / 4; ++i) {
        int p = sl + 4 * i;
        int2 fp = ((const int2*)p2l)[link * PLINK + p];
        ps += bf2f_(svb[fp.y * (N_FLOWS * DIM) + fp.x * DIM + j]);
    }
    ps += __shfl_xor(ps, 16, 64);
    ps += __shfl_xor(ps, 32, 64);
    float h = link_state[link * DIM + j];
    if (sl == 0) { xb_[li][j] = ps; hb_[li][j] = h; }
    float xv[16], hv[16];
#pragma unroll
    for (int q = 0; q < 4; ++q) {
        f32x4 x4 = ((const f32x4*)xb_[li])[q];
        f32x4 h4 = ((const f32x4*)hb_[li])[q];
#pragma unroll
        for (int e = 0; e < 4; ++e) { xv[q * 4 + e] = x4[e]; hv[q * 4 + e] = h4[e]; }
    }
    float az = NL2E * b[j], ar = NL2E * b[16 + j], ah = P2L2E * b[32 + j];
    float gz = NL2E * b[48 + j], gr = NL2E * b[64 + j], gh = P2L2E * b[80 + j];
    const float* kz = lWk_t + j * 48;
    const float* rz = lWr_t + j * 48;
#pragma unroll
    for (int k = 0; k < 16; ++k) {
        az = fmaf(xv[k], kz[k], az);
        ar = fmaf(xv[k], kz[16 + k], ar);
        ah = fmaf(xv[k], kz[32 + k], ah);
        gz = fmaf(hv[k], rz[k], gz);
        gr = fmaf(hv[k], rz[16 + k], gr);
        gh = fmaf(hv[k], rz[32 + k], gh);
    }
    float z = sigmoid2_(az + gz);
    float r = sigmoid2_(ar + gr);
    float cand = tanh2_(fmaf(r, gh, ah));
    float hn = fmaf(z, h - cand, cand);
    if (sl == 0) {
        link_state[link * DIM + j] = hn;
        hb_[li][j] = hn;
    }
    float nv[16];
#pragma unroll
    for (int q = 0; q < 4; ++q) {
        f32x4 n4 = ((const f32x4*)hb_[li])[q];
#pragma unroll
        for (int e = 0; e < 4; ++e) nv[q * 4 + e] = n4[e];
    }
    int c = lane;
    if (c < 48) {
        const float* pw = pWk_t + c * 16;
        float a = (c < 32) ? (pb[c] + pb[48 + c]) : pb[c];
#pragma unroll
        for (int k = 0; k < 16; ++k) a = fmaf(nv[k], pw[k], a);
        float sc = (c < 32) ? NL2E : P2L2E;
        xform[link * 64 + (c & 15) * 4 + (c >> 4)] = a * sc;
    }
}

// ---- readout: MLP over fp32 sv[pos 1..8] -> softplus -> /cap -> sum ------
__global__ __launch_bounds__(256) void k_readout(
    const float* __restrict__ sv, const int* __restrict__ l2p,
    const float* __restrict__ link_capacity,
    const float* __restrict__ W1, const float* __restrict__ b1,
    const float* __restrict__ W2, const float* __restrict__ b2,
    const float* __restrict__ W3, const float* __restrict__ b3,
    float* __restrict__ out) {
    int tid = blockIdx.x * 256 + threadIdx.x;
    int f = tid >> 3;
    int t = tid & 7;
    if (f >= N_FLOWS) return;
    const float* s = sv + (t + 1) * (N_FLOWS * DIM) + f * DIM;
    float h1[8];
#pragma unroll
    for (int m_ = 0; m_ < 8; ++m_) {
        float a = b1[m_];
#pragma unroll
        for (int k = 0; k < 16; ++k) a = fmaf(s[k], W1[k * 8 + m_], a);
        h1[m_] = selu_(a);
    }
    float h2[4];
#pragma unroll
    for (int q = 0; q < 4; ++q) {
        float a = b2[q];
#pragma unroll
        for (int m_ = 0; m_ < 8; ++m_) a = fmaf(h1[m_], W2[m_ * 4 + q], a);
        h2[q] = selu_(a);
    }
    float o = b3[0];
#pragma unroll
    for (int q = 0; q < 4; ++q) o = fmaf(h2[q], W3[q], o);
    o = softplus_(o);
    int link = l2p[f * LPATH + t];
    float v = o * rcp_(link_capacity[link]);
    v += SWZ(v, 0x041F);
    v += SWZ(v, 0x081F);
    v += SWZ(v, 0x101F);
    if (t == 0) out[f] = v;
}

extern "C" void kernel_launch(void* const* d_in, const int* in_sizes, int n_in,
                              void* d_out, int out_size, void* d_ws, size_t ws_size,
                              hipStream_t stream) {
    const float* flow_traffic = (const float*)d_in[0];
    const float* flow_packets = (const float*)d_in[1];
    const float* max_link_load = (const float*)d_in[2];
    const float* flow_pkts_per_burst = (const float*)d_in[3];
    const float* flow_bitrate_per_burst = (const float*)d_in[4];
    const float* flow_packet_size = (const float*)d_in[5];
    const float* flow_type = (const float*)d_in[6];
    const float* flow_ipg_mean = (const float*)d_in[7];
    const float* ibg = (const float*)d_in[8];
    const float* flow_p90 = (const float*)d_in[9];
    const float* rate = (const float*)d_in[10];
    const float* flow_ipg_var = (const float*)d_in[11];
    const float* link_capacity = (const float*)d_in[12];
    const float* fe_W1 = (const float*)d_in[13];
    const float* fe_b1 = (const float*)d_in[14];
    const float* fe_W2 = (const float*)d_in[15];
    const float* fe_b2 = (const float*)d_in[16];
    const float* le_W1 = (const float*)d_in[17];
    const float* le_b1 = (const float*)d_in[18];
    const float* le_W2 = (const float*)d_in[19];
    const float* le_b2 = (const float*)d_in[20];
    const float* att_W = (const float*)d_in[21];
    const float* att_b = (const float*)d_in[22];
    const float* pgru_Wk = (const float*)d_in[23];
    const float* pgru_Wr = (const float*)d_in[24];
    const float* pgru_b = (const float*)d_in[25];
    const float* lgru_Wk = (const float*)d_in[26];
    const float* lgru_Wr = (const float*)d_in[27];
    const float* lgru_b = (const float*)d_in[28];
    const float* ro_W1 = (const float*)d_in[29];
    const float* ro_b1 = (const float*)d_in[30];
    const float* ro_W2 = (const float*)d_in[31];
    const float* ro_b2 = (const float*)d_in[32];
    const float* ro_W3 = (const float*)d_in[33];
    const float* ro_b3 = (const float*)d_in[34];
    const int* flow_length = (const int*)d_in[35];
    const int* l2p = (const int*)d_in[36];
    const int* p2l = (const int*)d_in[37];

    float* ws = (float*)d_ws;
    float* path_state = ws;                      // 800000
    float* link_state = ws + 800000;             // 80000
    float* sv = ws + 880000;                     // 7200000  [pos][flow][16] (fp32 view)
    ushort* svb = (ushort*)sv;                   // bf16 view, iters 0..10
    float* load = ws + 8080000;                  // 5000
    float* xform = ws + 8085000;                 // 320000   [link][16][4]
    ushort* wfrag = (ushort*)(ws + 8405000);     // 4096 ushort (2048 float slots)
    float* lWk_t = ws + 8407048;                 // 768
    float* lWr_t = ws + 8407816;                 // 768
    float* pWk_t = ws + 8408584;                 // 768
    if (ws_size < (size_t)8409352 * 4) return;

    k_prep<<<25, 256, 0, stream>>>(pgru_Wr, att_W, lgru_Wk, lgru_Wr, pgru_Wk,
                                   wfrag, lWk_t, lWr_t, pWk_t);
    k_load<<<(N_LINKS * 64 + 255) / 256, 256, 0, stream>>>(p2l, flow_traffic,
                                                           link_capacity, load);
    k_flow_init<<<(N_FLOWS + 255) / 256, 256, 0, stream>>>(
        flow_traffic, flow_packets, ibg, rate, flow_p90, flow_packet_size,
        flow_bitrate_per_burst, flow_ipg_mean, flow_ipg_var, flow_pkts_per_burst,
        flow_length, flow_type, fe_W1, fe_b1, fe_W2, fe_b2, path_state);
    k_link_init<<<(N_LINKS + 255) / 256, 256, 0, stream>>>(
        link_capacity, load, max_link_load, le_W1, le_b1, le_W2, le_b2,
        pgru_Wk, pgru_b, link_state, xform);

    int fp_grid = (N_FLOWS + 63) / 64;  // 16 flows/wave, 4 waves/block
    for (int it = 0; it < ITERS - 1; ++it) {
        k_flow_pass<false><<<fp_grid, 256, 0, stream>>>(
            l2p, xform, path_state, svb, sv, wfrag, pgru_b, att_b);
        k_link_pass<<<N_LINKS / 4, 256, 0, stream>>>(
            p2l, svb, link_state, lWk_t, lWr_t, lgru_b, pWk_t, pgru_b, xform);
    }
    // final iteration: write raw fp32 h history to sv; separate readout.
    k_flow_pass<true><<<fp_grid, 256, 0, stream>>>(
        l2p, xform, path_state, svb, sv, wfrag, pgru_b, att_b);
    k_readout<<<(N_FLOWS * 8 + 255) / 256, 256, 0, stream>>>(
        sv, l2p, link_capacity, ro_W1, ro_b1, ro_W2, ro_b2, ro_W3, ro_b3,
        (float*)d_out);
}

// Round 18
// 461.130 us; speedup vs baseline: 1.0145x; 1.0145x over previous
//
#include <hip/hip_runtime.h>
#include <hip/hip_bf16.h>

#define N_FLOWS 50000
#define N_LINKS 5000
#define LPATH 8
#define PLINK 80
#define DIM 16
#define ITERS 12

typedef __attribute__((ext_vector_type(4))) float f32x4;
typedef __attribute__((ext_vector_type(8))) short bf16x8;

#define L2E 1.4426950408889634f
#define NL2E (-1.4426950408889634f)
#define P2L2E 2.8853900817779268f

#define SWZ(x, pat) __int_as_float(__builtin_amdgcn_ds_swizzle(__float_as_int(x), (pat)))
#define MFMA16(A, B, C) __builtin_amdgcn_mfma_f32_16x16x32_bf16((A), (B), (C), 0, 0, 0)

template <int CTRL>
__device__ __forceinline__ float dppmov_(float x) {
    return __int_as_float(__builtin_amdgcn_update_dpp(
        0, __float_as_int(x), CTRL, 0xF, 0xF, true));
}
#define ROR1 0x121
#define ROR2 0x122
#define ROR4 0x124
#define ROR8 0x128

__device__ __forceinline__ float rcp_(float x) { return __builtin_amdgcn_rcpf(x); }
__device__ __forceinline__ float exp2_(float x) { return __builtin_amdgcn_exp2f(x); }
__device__ __forceinline__ float sigmoid2_(float s) { return rcp_(1.f + exp2_(s)); }
__device__ __forceinline__ float tanh2_(float s) { return 1.f - 2.f * rcp_(1.f + exp2_(s)); }
__device__ __forceinline__ float selu_(float x) {
    const float sc = 1.0507009873554805f, al = 1.6732632423543772f;
    return x > 0.f ? sc * x : sc * al * expm1f(x);
}
__device__ __forceinline__ float softplus_(float x) {
    return fmaxf(x, 0.f) + log1pf(__expf(-fabsf(x)));
}
__device__ __forceinline__ ushort f2bf_(float x) {
    unsigned u = __float_as_uint(x);
    u += 0x7fffu + ((u >> 16) & 1u);
    return (ushort)(u >> 16);
}
__device__ __forceinline__ float bf2f_(ushort h) {
    return __uint_as_float(((unsigned)h) << 16);
}

// ---- one-time weight repack ----------------------------------------------
// wfrag[gate*2+isLo][lane][e] bf16: B-fragment; slot (lane,e) holds
// W[((lane>>4)*8+e)&15][lane&15] -- BOTH K-halves carry the same W rows, so
// A=[h_hi|h_lo] x B=[W|W] sums hi+lo contributions in one MFMA.
// hi frag = bf16(W*scale); lo frag = bf16(W*scale - hi).
__global__ __launch_bounds__(256) void k_prep(
    const float* __restrict__ pWr, const float* __restrict__ attW,
    const float* __restrict__ lWk, const float* __restrict__ lWr,
    const float* __restrict__ pWk,
    ushort* __restrict__ wfrag, float* __restrict__ lWk_t,
    float* __restrict__ lWr_t, float* __restrict__ pWk_t) {
    int i = blockIdx.x * 256 + threadIdx.x;
    if (i < 768) {
        int t = i;
        int j = t / 48, r = t % 48;
        float sc = (r / 16) == 2 ? P2L2E : NL2E;
        lWk_t[t] = lWk[(r % 16) * 48 + (r / 16) * 16 + j] * sc;
    } else if (i < 1536) {
        int t = i - 768;
        int j = t / 48, r = t % 48;
        float sc = (r / 16) == 2 ? P2L2E : NL2E;
        lWr_t[t] = lWr[(r % 16) * 48 + (r / 16) * 16 + j] * sc;
    } else if (i < 2304) {
        int t = i - 1536;
        pWk_t[t] = pWk[(t % 16) * 48 + (t / 16)];
    } else if (i < 6400) {
        int t = i - 2304;            // 0..4095
        int frag = t >> 9;           // 0..7 = gate*2 + isLo
        int s = t & 511;
        int lane = s >> 3;
        int e = s & 7;
        int gate = frag >> 1;
        int isLo = frag & 1;
        int n = lane & 15;
        int k = ((lane >> 4) * 8 + e) & 15;   // W rows repeat across K-halves
        float raw;
        if (gate < 3) {
            float sc = gate == 2 ? P2L2E : NL2E;
            raw = pWr[k * 48 + gate * 16 + n] * sc;
        } else {
            raw = attW[k * 16 + n] * L2E;
        }
        ushort hi = f2bf_(raw);
        wfrag[t] = isLo ? f2bf_(raw - bf2f_(hi)) : hi;
    }
}

// ---- load per link -------------------------------------------------------
__global__ __launch_bounds__(256) void k_load(const int* __restrict__ p2l,
                                              const float* __restrict__ flow_traffic,
                                              const float* __restrict__ link_capacity,
                                              float* __restrict__ load) {
    int wave = (blockIdx.x * 256 + threadIdx.x) >> 6;
    int lane = threadIdx.x & 63;
    if (wave >= N_LINKS) return;
    float s = 0.f;
    for (int p = lane; p < PLINK; p += 64) {
        int flow = p2l[(wave * PLINK + p) * 2];
        s += flow_traffic[flow];
    }
#pragma unroll
    for (int off = 32; off; off >>= 1) s += __shfl_xor(s, off, 64);
    if (lane == 0) load[wave] = s / (link_capacity[wave] * 1e9f);
}

// ---- flow embedding ------------------------------------------------------
__global__ __launch_bounds__(256) void k_flow_init(
    const float* __restrict__ flow_traffic, const float* __restrict__ flow_packets,
    const float* __restrict__ ibg, const float* __restrict__ rate,
    const float* __restrict__ p90, const float* __restrict__ pkt_size,
    const float* __restrict__ bitrate_pb, const float* __restrict__ ipg_mean,
    const float* __restrict__ ipg_var, const float* __restrict__ pkts_pb,
    const int* __restrict__ flow_length, const float* __restrict__ flow_type,
    const float* __restrict__ W1, const float* __restrict__ b1,
    const float* __restrict__ W2, const float* __restrict__ b2,
    float* __restrict__ path_state) {
    int f = blockIdx.x * 256 + threadIdx.x;
    if (f >= N_FLOWS) return;
    float feats[13];
    feats[0] = (flow_traffic[f] - 0.1f) * 2.f;
    feats[1] = (flow_packets[f] - 0.1f) * 2.f;
    feats[2] = (ibg[f] - 0.1f) * 2.f;
    feats[3] = (rate[f] - 0.1f) * 2.f;
    feats[4] = (p90[f] - 0.1f) * 2.f;
    feats[5] = (pkt_size[f] - 0.1f) * 2.f;
    feats[6] = (bitrate_pb[f] - 0.1f) * 2.f;
    feats[7] = (ipg_mean[f] - 0.1f) * 2.f;
    feats[8] = (ipg_var[f] - 0.1f) * 2.f;
    feats[9] = (pkts_pb[f] - 0.1f) * 2.f;
    feats[10] = (float)flow_length[f];
    feats[11] = flow_type[f * 2 + 0];
    feats[12] = flow_type[f * 2 + 1];
    float h1[DIM];
#pragma unroll
    for (int j = 0; j < DIM; ++j) {
        float a = b1[j];
#pragma unroll
        for (int k = 0; k < 13; ++k) a = fmaf(feats[k], W1[k * DIM + j], a);
        h1[j] = selu_(a);
    }
#pragma unroll
    for (int j = 0; j < DIM; ++j) {
        float a = b2[j];
#pragma unroll
        for (int k = 0; k < DIM; ++k) a = fmaf(h1[k], W2[k * DIM + j], a);
        path_state[f * DIM + j] = selu_(a);
    }
}

// ---- link embedding + xform precompute -----------------------------------
__global__ __launch_bounds__(256) void k_link_init(
    const float* __restrict__ link_capacity, const float* __restrict__ load,
    const float* __restrict__ max_link_load,
    const float* __restrict__ W1, const float* __restrict__ b1,
    const float* __restrict__ W2, const float* __restrict__ b2,
    const float* __restrict__ pWk, const float* __restrict__ pb,
    float* __restrict__ link_state, float* __restrict__ xform) {
    int l = blockIdx.x * 256 + threadIdx.x;
    if (l >= N_LINKS) return;
    float feats[3];
    feats[0] = (link_capacity[l] - 0.1f) * 2.f;
    feats[1] = load[l];
    feats[2] = load[l] / max_link_load[0];
    float h1[DIM];
#pragma unroll
    for (int j = 0; j < DIM; ++j) {
        float a = b1[j];
#pragma unroll
        for (int k = 0; k < 3; ++k) a = fmaf(feats[k], W1[k * DIM + j], a);
        h1[j] = selu_(a);
    }
    float h2[DIM];
#pragma unroll
    for (int j = 0; j < DIM; ++j) {
        float a = b2[j];
#pragma unroll
        for (int k = 0; k < DIM; ++k) a = fmaf(h1[k], W2[k * DIM + j], a);
        h2[j] = selu_(a);
        link_state[l * DIM + j] = h2[j];
    }
#pragma unroll
    for (int c = 0; c < 3 * DIM; ++c) {
        float a = (c < 32) ? (pb[c] + pb[48 + c]) : pb[c];
#pragma unroll
        for (int k = 0; k < DIM; ++k) a = fmaf(h2[k], pWk[k * 48 + c], a);
        float sc = (c < 32) ? NL2E : P2L2E;
        xform[l * 64 + (c & 15) * 4 + (c >> 4)] = a * sc;
    }
}

// ---- flow pass: MFMA GRU (double-bf16 split), 16 flows per wave ----------
// C/D layout: col j = lane&15, row flow = (lane>>4)*4 + reg.
// A = [h_hi | h_lo] across K=32; B = [W_hi|W_hi] then [W_lo|W_lo].
// Non-LAST sv stores are bf16; LAST writes fp32 h via float view.
template <bool LAST>
__global__ __launch_bounds__(256) void k_flow_pass(
    const int* __restrict__ l2p, const float* __restrict__ xform,
    float* __restrict__ path_state, ushort* __restrict__ svb,
    float* __restrict__ svf,
    const ushort* __restrict__ wfrag, const float* __restrict__ b,
    const float* __restrict__ attB) {
    __shared__ __align__(16) ushort hx[4][16][40];  // cols 0-15 hi, 16-31 lo
    __shared__ int lnk[4][16][8];
    int tid = threadIdx.x;
    int wid = tid >> 6, lane = tid & 63;
    int g = lane >> 4, j = lane & 15;
    int fbase = blockIdx.x * 64 + wid * 16;
    {   // stage this wave's 16x8 link table (wave-private, no barrier needed)
        int lf = lane >> 2;
        int off = (lane & 3) * 2;
        int fc = fbase + lf; if (fc >= N_FLOWS) fc = N_FLOWS - 1;
        *(int2*)&lnk[wid][lf][off] = *(const int2*)(l2p + fc * LPATH + off);
    }
    bf16x8 WzH = *(const bf16x8*)(wfrag + (0 * 512 + lane * 8));
    bf16x8 WzL = *(const bf16x8*)(wfrag + (1 * 512 + lane * 8));
    bf16x8 WrH = *(const bf16x8*)(wfrag + (2 * 512 + lane * 8));
    bf16x8 WrL = *(const bf16x8*)(wfrag + (3 * 512 + lane * 8));
    bf16x8 WhH = *(const bf16x8*)(wfrag + (4 * 512 + lane * 8));
    bf16x8 WhL = *(const bf16x8*)(wfrag + (5 * 512 + lane * 8));
    bf16x8 WaH = *(const bf16x8*)(wfrag + (6 * 512 + lane * 8));
    bf16x8 WaL = *(const bf16x8*)(wfrag + (7 * 512 + lane * 8));
    float bh = P2L2E * b[80 + j];
    float ab = L2E * attB[j];
    f32x4 bhv = {bh, bh, bh, bh};
    f32x4 abv = {ab, ab, ab, ab};
    f32x4 zero = {0.f, 0.f, 0.f, 0.f};
    int fr[4];
    f32x4 hC;
#pragma unroll
    for (int r = 0; r < 4; ++r) {
        fr[r] = fbase + g * 4 + r;
        int fc = fr[r] < N_FLOWS ? fr[r] : N_FLOWS - 1;
        hC[r] = path_state[fc * DIM + j];
    }
#pragma unroll
    for (int p = 0; p <= LPATH; ++p) {
        bf16x8 A = {};
        if (!LAST || p < LPATH) {
            // split h -> hi+lo and transpose (C-layout -> A-frag) via LDS
#pragma unroll
            for (int r = 0; r < 4; ++r) {
                ushort hi = f2bf_(hC[r]);
                hx[wid][g * 4 + r][j] = hi;
                hx[wid][g * 4 + r][16 + j] = f2bf_(hC[r] - bf2f_(hi));
            }
            A = *(const bf16x8*)&hx[wid][j][g * 8];
        }
        if constexpr (!LAST) {
            f32x4 att = MFMA16(A, WaH, abv);
            att = MFMA16(A, WaL, att);
#pragma unroll
            for (int r = 0; r < 4; ++r) {
                float a = att[r];
                a = a > 0.f ? a : 0.01f * a;  // leaky (scale-safe)
                float m = a;
                m = fmaxf(m, dppmov_<ROR1>(m));
                m = fmaxf(m, dppmov_<ROR2>(m));
                m = fmaxf(m, dppmov_<ROR4>(m));
                m = fmaxf(m, dppmov_<ROR8>(m));
                float e = exp2_(a - m);
                float s = e;
                s += dppmov_<ROR1>(s);
                s += dppmov_<ROR2>(s);
                s += dppmov_<ROR4>(s);
                s += dppmov_<ROR8>(s);
                if (fr[r] < N_FLOWS)
                    svb[p * (N_FLOWS * DIM) + fr[r] * DIM + j] =
                        f2bf_(e * rcp_(s) * hC[r]);
            }
        } else {
            if (p > 0) {
#pragma unroll
                for (int r = 0; r < 4; ++r)
                    if (fr[r] < N_FLOWS)
                        svf[p * (N_FLOWS * DIM) + fr[r] * DIM + j] = hC[r];
            }
        }
        if (p < LPATH) {
            f32x4 Gz = MFMA16(A, WzH, zero);
            Gz = MFMA16(A, WzL, Gz);
            f32x4 Gr = MFMA16(A, WrH, zero);
            Gr = MFMA16(A, WrL, Gr);
            f32x4 Gh = MFMA16(A, WhH, bhv);
            Gh = MFMA16(A, WhL, Gh);
#pragma unroll
            for (int r = 0; r < 4; ++r) {
                int link = lnk[wid][g * 4 + r][p];
                f32x4 xq = *(const f32x4*)(xform + link * 64 + j * 4);
                float z = sigmoid2_(xq[0] + Gz[r]);
                float rr = sigmoid2_(xq[1] + Gr[r]);
                float cand = tanh2_(fmaf(rr, Gh[r], xq[2]));
                hC[r] = fmaf(z, hC[r] - cand, cand);
            }
        }
    }
    if constexpr (!LAST) {
#pragma unroll
        for (int r = 0; r < 4; ++r)
            if (fr[r] < N_FLOWS) path_state[fr[r] * DIM + j] = hC[r];
    }
}

// ---- link pass: bf16 gather-sum + link GRU (exp2 gates) + fused xform ----
__global__ __launch_bounds__(256, 4) void k_link_pass(
    const int* __restrict__ p2l, const ushort* __restrict__ svb,
    float* __restrict__ link_state,
    const float* __restrict__ lWk_t, const float* __restrict__ lWr_t,
    const float* __restrict__ b,
    const float* __restrict__ pWk_t, const float* __restrict__ pb,
    float* __restrict__ xform) {
    __shared__ float xb_[4][16];
    __shared__ float hb_[4][16];
    int tid = threadIdx.x;
    int li = tid >> 6;
    int lane = tid & 63;
    int sl = lane >> 4, j = lane & 15;
    int link = blockIdx.x * 4 + li;
    float ps = 0.f;
#pragma unroll 4
    for (int i = 0; i < PLINK / 4; ++i) {
        int p = sl + 4 * i;
        int2 fp = ((const int2*)p2l)[link * PLINK + p];
        ps += bf2f_(svb[fp.y * (N_FLOWS * DIM) + fp.x * DIM + j]);
    }
    ps += __shfl_xor(ps, 16, 64);
    ps += __shfl_xor(ps, 32, 64);
    float h = link_state[link * DIM + j];
    if (sl == 0) { xb_[li][j] = ps; hb_[li][j] = h; }
    float xv[16], hv[16];
#pragma unroll
    for (int q = 0; q < 4; ++q) {
        f32x4 x4 = ((const f32x4*)xb_[li])[q];
        f32x4 h4 = ((const f32x4*)hb_[li])[q];
#pragma unroll
        for (int e = 0; e < 4; ++e) { xv[q * 4 + e] = x4[e]; hv[q * 4 + e] = h4[e]; }
    }
    float az = NL2E * b[j], ar = NL2E * b[16 + j], ah = P2L2E * b[32 + j];
    float gz = NL2E * b[48 + j], gr = NL2E * b[64 + j], gh = P2L2E * b[80 + j];
    const float* kz = lWk_t + j * 48;
    const float* rz = lWr_t + j * 48;
#pragma unroll
    for (int k = 0; k < 16; ++k) {
        az = fmaf(xv[k], kz[k], az);
        ar = fmaf(xv[k], kz[16 + k], ar);
        ah = fmaf(xv[k], kz[32 + k], ah);
        gz = fmaf(hv[k], rz[k], gz);
        gr = fmaf(hv[k], rz[16 + k], gr);
        gh = fmaf(hv[k], rz[32 + k], gh);
    }
    float z = sigmoid2_(az + gz);
    float r = sigmoid2_(ar + gr);
    float cand = tanh2_(fmaf(r, gh, ah));
    float hn = fmaf(z, h - cand, cand);
    if (sl == 0) {
        link_state[link * DIM + j] = hn;
        hb_[li][j] = hn;
    }
    float nv[16];
#pragma unroll
    for (int q = 0; q < 4; ++q) {
        f32x4 n4 = ((const f32x4*)hb_[li])[q];
#pragma unroll
        for (int e = 0; e < 4; ++e) nv[q * 4 + e] = n4[e];
    }
    int c = lane;
    if (c < 48) {
        const float* pw = pWk_t + c * 16;
        float a = (c < 32) ? (pb[c] + pb[48 + c]) : pb[c];
#pragma unroll
        for (int k = 0; k < 16; ++k) a = fmaf(nv[k], pw[k], a);
        float sc = (c < 32) ? NL2E : P2L2E;
        xform[link * 64 + (c & 15) * 4 + (c >> 4)] = a * sc;
    }
}

// ---- readout: MLP over fp32 sv[pos 1..8] -> softplus -> /cap -> sum ------
__global__ __launch_bounds__(256) void k_readout(
    const float* __restrict__ sv, const int* __restrict__ l2p,
    const float* __restrict__ link_capacity,
    const float* __restrict__ W1, const float* __restrict__ b1,
    const float* __restrict__ W2, const float* __restrict__ b2,
    const float* __restrict__ W3, const float* __restrict__ b3,
    float* __restrict__ out) {
    int tid = blockIdx.x * 256 + threadIdx.x;
    int f = tid >> 3;
    int t = tid & 7;
    if (f >= N_FLOWS) return;
    const float* s = sv + (t + 1) * (N_FLOWS * DIM) + f * DIM;
    float h1[8];
#pragma unroll
    for (int m_ = 0; m_ < 8; ++m_) {
        float a = b1[m_];
#pragma unroll
        for (int k = 0; k < 16; ++k) a = fmaf(s[k], W1[k * 8 + m_], a);
        h1[m_] = selu_(a);
    }
    float h2[4];
#pragma unroll
    for (int q = 0; q < 4; ++q) {
        float a = b2[q];
#pragma unroll
        for (int m_ = 0; m_ < 8; ++m_) a = fmaf(h1[m_], W2[m_ * 4 + q], a);
        h2[q] = selu_(a);
    }
    float o = b3[0];
#pragma unroll
    for (int q = 0; q < 4; ++q) o = fmaf(h2[q], W3[q], o);
    o = softplus_(o);
    int link = l2p[f * LPATH + t];
    float v = o * rcp_(link_capacity[link]);
    v += SWZ(v, 0x041F);
    v += SWZ(v, 0x081F);
    v += SWZ(v, 0x101F);
    if (t == 0) out[f] = v;
}

extern "C" void kernel_launch(void* const* d_in, const int* in_sizes, int n_in,
                              void* d_out, int out_size, void* d_ws, size_t ws_size,
                              hipStream_t stream) {
    const float* flow_traffic = (const float*)d_in[0];
    const float* flow_packets = (const float*)d_in[1];
    const float* max_link_load = (const float*)d_in[2];
    const float* flow_pkts_per_burst = (const float*)d_in[3];
    const float* flow_bitrate_per_burst = (const float*)d_in[4];
    const float* flow_packet_size = (const float*)d_in[5];
    const float* flow_type = (const float*)d_in[6];
    const float* flow_ipg_mean = (const float*)d_in[7];
    const float* ibg = (const float*)d_in[8];
    const float* flow_p90 = (const float*)d_in[9];
    const float* rate = (const float*)d_in[10];
    const float* flow_ipg_var = (const float*)d_in[11];
    const float* link_capacity = (const float*)d_in[12];
    const float* fe_W1 = (const float*)d_in[13];
    const float* fe_b1 = (const float*)d_in[14];
    const float* fe_W2 = (const float*)d_in[15];
    const float* fe_b2 = (const float*)d_in[16];
    const float* le_W1 = (const float*)d_in[17];
    const float* le_b1 = (const float*)d_in[18];
    const float* le_W2 = (const float*)d_in[19];
    const float* le_b2 = (const float*)d_in[20];
    const float* att_W = (const float*)d_in[21];
    const float* att_b = (const float*)d_in[22];
    const float* pgru_Wk = (const float*)d_in[23];
    const float* pgru_Wr = (const float*)d_in[24];
    const float* pgru_b = (const float*)d_in[25];
    const float* lgru_Wk = (const float*)d_in[26];
    const float* lgru_Wr = (const float*)d_in[27];
    const float* lgru_b = (const float*)d_in[28];
    const float* ro_W1 = (const float*)d_in[29];
    const float* ro_b1 = (const float*)d_in[30];
    const float* ro_W2 = (const float*)d_in[31];
    const float* ro_b2 = (const float*)d_in[32];
    const float* ro_W3 = (const float*)d_in[33];
    const float* ro_b3 = (const float*)d_in[34];
    const int* flow_length = (const int*)d_in[35];
    const int* l2p = (const int*)d_in[36];
    const int* p2l = (const int*)d_in[37];

    float* ws = (float*)d_ws;
    float* path_state = ws;                      // 800000
    float* link_state = ws + 800000;             // 80000
    float* sv = ws + 880000;                     // 7200000  [pos][flow][16] (fp32 view)
    ushort* svb = (ushort*)sv;                   // bf16 view, iters 0..10
    float* load = ws + 8080000;                  // 5000
    float* xform = ws + 8085000;                 // 320000   [link][16][4]
    ushort* wfrag = (ushort*)(ws + 8405000);     // 4096 ushort (2048 float slots)
    float* lWk_t = ws + 8407048;                 // 768
    float* lWr_t = ws + 8407816;                 // 768
    float* pWk_t = ws + 8408584;                 // 768
    if (ws_size < (size_t)8409352 * 4) return;

    k_prep<<<25, 256, 0, stream>>>(pgru_Wr, att_W, lgru_Wk, lgru_Wr, pgru_Wk,
                                   wfrag, lWk_t, lWr_t, pWk_t);
    k_load<<<(N_LINKS * 64 + 255) / 256, 256, 0, stream>>>(p2l, flow_traffic,
                                                           link_capacity, load);
    k_flow_init<<<(N_FLOWS + 255) / 256, 256, 0, stream>>>(
        flow_traffic, flow_packets, ibg, rate, flow_p90, flow_packet_size,
        flow_bitrate_per_burst, flow_ipg_mean, flow_ipg_var, flow_pkts_per_burst,
        flow_length, flow_type, fe_W1, fe_b1, fe_W2, fe_b2, path_state);
    k_link_init<<<(N_LINKS + 255) / 256, 256, 0, stream>>>(
        link_capacity, load, max_link_load, le_W1, le_b1, le_W2, le_b2,
        pgru_Wk, pgru_b, link_state, xform);

    int fp_grid = (N_FLOWS + 63) / 64;  // 16 flows/wave, 4 waves/block
    for (int it = 0; it < ITERS - 1; ++it) {
        k_flow_pass<false><<<fp_grid, 256, 0, stream>>>(
            l2p, xform, path_state, svb, sv, wfrag, pgru_b, att_b);
        k_link_pass<<<N_LINKS / 4, 256, 0, stream>>>(
            p2l, svb, link_state, lWk_t, lWr_t, lgru_b, pWk_t, pgru_b, xform);
    }
    // final iteration: write raw fp32 h history to sv; separate readout.
    k_flow_pass<true><<<fp_grid, 256, 0, stream>>>(
        l2p, xform, path_state, svb, sv, wfrag, pgru_b, att_b);
    k_readout<<<(N_FLOWS * 8 + 255) / 256, 256, 0, stream>>>(
        sv, l2p, link_capacity, ro_W1, ro_b1, ro_W2, ro_b2, ro_W3, ro_b3,
        (float*)d_out);
}